// Round 1
// baseline (39948.746 us; speedup 1.0000x reference)
//
#include <hip/hip_runtime.h>

#define BATCH 256
#define SEQ   1024
#define HID   256

// ---------- fast activations (fp32, ~2 ulp) ----------
__device__ __forceinline__ float tanh_fast(float x) {
    float e = __expf(2.0f * x);          // inf-safe: x>>0 -> 1, x<<0 -> -1
    return 1.0f - 2.0f / (e + 1.0f);
}
__device__ __forceinline__ float sigmoid_fast(float x) {
    return 1.0f / (1.0f + __expf(-x));
}

// ---------- MLP ----------
template<int DIN, int DOUT, bool ACT>
__device__ __forceinline__ void dense(const float* __restrict__ w,
                                      const float* __restrict__ b,
                                      const float* hin, float* hout) {
    #pragma unroll
    for (int i = 0; i < DOUT; i++) {
        float a = b[i];
        #pragma unroll
        for (int j = 0; j < DIN; j++) a = fmaf(w[i * DIN + j], hin[j], a);
        hout[i] = ACT ? tanh_fast(a) : a;
    }
}

__global__ __launch_bounds__(256) void mlp_kernel(
    const float* __restrict__ x,
    const float* __restrict__ w1, const float* __restrict__ b1,
    const float* __restrict__ w2, const float* __restrict__ b2,
    const float* __restrict__ w3, const float* __restrict__ b3,
    const float* __restrict__ w4, const float* __restrict__ b4,
    const float* __restrict__ w5, const float* __restrict__ b5,
    const float* __restrict__ w6, const float* __restrict__ b6,
    const float* __restrict__ w7, const float* __restrict__ b7,
    float* __restrict__ cnn_out, float* __restrict__ xT)
{
    int n = blockIdx.x * 256 + threadIdx.x;          // n = b*SEQ + s
    float h0[1] = { x[n] };
    float h1[16], h2[16], h3[12], h4[8], h5[4], h6[4], h7[1];
    dense<1, 16, true >(w1, b1, h0, h1);
    dense<16, 16, true >(w2, b2, h1, h2);
    dense<16, 12, true >(w3, b3, h2, h3);
    dense<12, 8, true >(w4, b4, h3, h4);
    dense<8, 4, true >(w5, b5, h4, h5);
    dense<4, 4, true >(w6, b6, h5, h6);
    dense<4, 1, false>(w7, b7, h6, h7);
    cnn_out[n] = h7[0];
    int b = n >> 10, s = n & 1023;
    xT[s * BATCH + b] = h7[0];                        // time-major copy for LSTM
}

// ---------- weight pack: wpack[k][j] = (wf, wi, wg, wo)[j][k], k=0..256 ----------
__global__ __launch_bounds__(256) void pack_kernel(
    const float* __restrict__ wf, const float* __restrict__ wi,
    const float* __restrict__ wg, const float* __restrict__ wo,
    float4* __restrict__ wpack)
{
    int tid = blockIdx.x * 256 + threadIdx.x;        // 257*256 threads
    int j = tid & 255;
    int k = tid >> 8;
    int src = j * 257 + k;
    wpack[k * 256 + j] = make_float4(wf[src], wi[src], wg[src], wo[src]);
}

// ---------- LSTM: one block per batch element, thread j owns hidden unit j ----------
#define G1 7   // k-groups (of 4) cached in LDS  -> 28 k columns, 112 KB
#define G2 8   // k-groups (of 4) cached in regs -> 32 k columns, 128 VGPR

#define GATE_FMA(W, HV)                      \
    acc.x = fmaf((W).x, (HV), acc.x);        \
    acc.y = fmaf((W).y, (HV), acc.y);        \
    acc.z = fmaf((W).z, (HV), acc.z);        \
    acc.w = fmaf((W).w, (HV), acc.w);

__global__ __launch_bounds__(256, 1) void lstm_kernel(
    const float* __restrict__ xT,
    const float4* __restrict__ wpack,
    const float* __restrict__ bf, const float* __restrict__ bi,
    const float* __restrict__ bg, const float* __restrict__ bo,
    const float* __restrict__ w_head, const float* __restrict__ b_head,
    float* __restrict__ logits)
{
    __shared__ float4 wlds[G1 * 4][256];             // 112 KB
    __shared__ __align__(16) float hx_s[HID];
    __shared__ float red[256];

    const int b = blockIdx.x;
    const int j = threadIdx.x;

    const float4 bias = make_float4(bf[j], bi[j], bg[j], bo[j]);
    const float4 w0 = wpack[j];                      // k=0: input column
    float4 wreg[G2 * 4];
    #pragma unroll
    for (int r = 0; r < G2 * 4; r++) wreg[r] = wpack[(1 + G1 * 4 + r) * 256 + j];
    #pragma unroll
    for (int r = 0; r < G1 * 4; r++) wlds[r][j] = wpack[(1 + r) * 256 + j];
    hx_s[j] = 0.0f;
    float cx = 0.0f, hj = 0.0f;
    __syncthreads();

    const float4* __restrict__ hx4 = (const float4*)hx_s;
    const float4* __restrict__ wrow = wpack + j;

    for (int t = 0; t < SEQ; t++) {
        float xt = xT[t * BATCH + b];                // uniform per block -> scalar load
        float4 acc = bias;
        GATE_FMA(w0, xt);
        #pragma unroll
        for (int g = 0; g < G1; ++g) {               // LDS-cached columns
            float4 h4 = hx4[g];
            GATE_FMA(wlds[4 * g + 0][j], h4.x);
            GATE_FMA(wlds[4 * g + 1][j], h4.y);
            GATE_FMA(wlds[4 * g + 2][j], h4.z);
            GATE_FMA(wlds[4 * g + 3][j], h4.w);
        }
        #pragma unroll
        for (int g = 0; g < G2; ++g) {               // register-cached columns
            float4 h4 = hx4[G1 + g];
            GATE_FMA(wreg[4 * g + 0], h4.x);
            GATE_FMA(wreg[4 * g + 1], h4.y);
            GATE_FMA(wreg[4 * g + 2], h4.z);
            GATE_FMA(wreg[4 * g + 3], h4.w);
        }
        #pragma unroll
        for (int g = G1 + G2; g < 64; ++g) {         // streamed from L2
            float4 h4 = hx4[g];
            float4 wA = wrow[(1 + 4 * g + 0) * 256];
            float4 wB = wrow[(1 + 4 * g + 1) * 256];
            float4 wC = wrow[(1 + 4 * g + 2) * 256];
            float4 wD = wrow[(1 + 4 * g + 3) * 256];
            GATE_FMA(wA, h4.x);
            GATE_FMA(wB, h4.y);
            GATE_FMA(wC, h4.z);
            GATE_FMA(wD, h4.w);
        }
        float f = sigmoid_fast(acc.x);
        float i = sigmoid_fast(acc.y);
        float g = tanh_fast(acc.z);
        float o = sigmoid_fast(acc.w);
        cx = fmaf(f, cx, i * g);
        hj = o * tanh_fast(cx);
        __syncthreads();                             // all reads of hx done
        hx_s[j] = hj;
        __syncthreads();                             // new hx visible
    }

    // head: logits[b] = sum_j w_head[j]*hx[j] + b_head
    red[j] = w_head[j] * hj;
    __syncthreads();
    #pragma unroll
    for (int off = 128; off > 0; off >>= 1) {
        if (j < off) red[j] += red[j + off];
        __syncthreads();
    }
    if (j == 0) logits[b] = red[0] + b_head[0];
}

extern "C" void kernel_launch(void* const* d_in, const int* in_sizes, int n_in,
                              void* d_out, int out_size, void* d_ws, size_t ws_size,
                              hipStream_t stream) {
    const float* x      = (const float*)d_in[0];
    const float* w1     = (const float*)d_in[1];
    const float* b1     = (const float*)d_in[2];
    const float* w2     = (const float*)d_in[3];
    const float* b2     = (const float*)d_in[4];
    const float* w3     = (const float*)d_in[5];
    const float* b3     = (const float*)d_in[6];
    const float* w4     = (const float*)d_in[7];
    const float* b4     = (const float*)d_in[8];
    const float* w5     = (const float*)d_in[9];
    const float* b5     = (const float*)d_in[10];
    const float* w6     = (const float*)d_in[11];
    const float* b6     = (const float*)d_in[12];
    const float* w7     = (const float*)d_in[13];
    const float* b7     = (const float*)d_in[14];
    const float* w_f    = (const float*)d_in[15];
    const float* b_f    = (const float*)d_in[16];
    const float* w_i    = (const float*)d_in[17];
    const float* b_i    = (const float*)d_in[18];
    const float* w_g    = (const float*)d_in[19];
    const float* b_g    = (const float*)d_in[20];
    const float* w_o    = (const float*)d_in[21];
    const float* b_o    = (const float*)d_in[22];
    const float* w_head = (const float*)d_in[23];
    const float* b_head = (const float*)d_in[24];

    float*  out   = (float*)d_out;                   // [0..262143] cnn_features, [262144..] logits
    float*  xT    = (float*)d_ws;                    // 1 MB time-major features
    float4* wpack = (float4*)((char*)d_ws + (1 << 20)); // 1.05 MB packed gate weights

    pack_kernel<<<257, 256, 0, stream>>>(w_f, w_i, w_g, w_o, wpack);
    mlp_kernel<<<(BATCH * SEQ) / 256, 256, 0, stream>>>(
        x, w1, b1, w2, b2, w3, b3, w4, b4, w5, b5, w6, b6, w7, b7, out, xT);
    lstm_kernel<<<BATCH, 256, 0, stream>>>(
        xT, wpack, b_f, b_i, b_g, b_o, w_head, b_head, out + BATCH * SEQ);
}

// Round 2
// 21794.124 us; speedup vs baseline: 1.8330x; 1.8330x over previous
//
#include <hip/hip_runtime.h>

#define BATCH 256
#define SEQ   1024
#define HID   256
#define KG    4      // k-groups (k dimension split across groups of waves)
#define COLS  64     // hx columns per group (KG*COLS == HID)

// ---------- fast activations (fp32, ~2 ulp) ----------
__device__ __forceinline__ float tanh_fast(float x) {
    float e = __expf(2.0f * x);          // inf-safe: x>>0 -> 1, x<<0 -> -1
    return 1.0f - 2.0f / (e + 1.0f);
}
__device__ __forceinline__ float sigmoid_fast(float x) {
    return 1.0f / (1.0f + __expf(-x));
}

// ---------- MLP ----------
template<int DIN, int DOUT, bool ACT>
__device__ __forceinline__ void dense(const float* __restrict__ w,
                                      const float* __restrict__ b,
                                      const float* hin, float* hout) {
    #pragma unroll
    for (int i = 0; i < DOUT; i++) {
        float a = b[i];
        #pragma unroll
        for (int j = 0; j < DIN; j++) a = fmaf(w[i * DIN + j], hin[j], a);
        hout[i] = ACT ? tanh_fast(a) : a;
    }
}

__global__ __launch_bounds__(256) void mlp_kernel(
    const float* __restrict__ x,
    const float* __restrict__ w1, const float* __restrict__ b1,
    const float* __restrict__ w2, const float* __restrict__ b2,
    const float* __restrict__ w3, const float* __restrict__ b3,
    const float* __restrict__ w4, const float* __restrict__ b4,
    const float* __restrict__ w5, const float* __restrict__ b5,
    const float* __restrict__ w6, const float* __restrict__ b6,
    const float* __restrict__ w7, const float* __restrict__ b7,
    float* __restrict__ cnn_out)
{
    int n = blockIdx.x * 256 + threadIdx.x;          // n = b*SEQ + s
    float h0[1] = { x[n] };
    float h1[16], h2[16], h3[12], h4[8], h5[4], h6[4], h7[1];
    dense<1, 16, true >(w1, b1, h0, h1);
    dense<16, 16, true >(w2, b2, h1, h2);
    dense<16, 12, true >(w3, b3, h2, h3);
    dense<12, 8, true >(w4, b4, h3, h4);
    dense<8, 4, true >(w5, b5, h4, h5);
    dense<4, 4, true >(w6, b6, h5, h6);
    dense<4, 1, false>(w7, b7, h6, h7);
    cnn_out[n] = h7[0];                              // (b,s) row-major == what LSTM wants
}

// ---------- weight pack: wpack[k][j] = (wf, wi, wg, wo)[j][k], k=0..256 ----------
__global__ __launch_bounds__(256) void pack_kernel(
    const float* __restrict__ wf, const float* __restrict__ wi,
    const float* __restrict__ wg, const float* __restrict__ wo,
    float4* __restrict__ wpack)
{
    int j = threadIdx.x;
    int k = blockIdx.x;                              // 257 blocks
    int src = j * 257 + k;
    wpack[k * 256 + j] = make_float4(wf[src], wi[src], wg[src], wo[src]);
}

#define GATE_FMA(W, HV)                      \
    acc.x = fmaf((W).x, (HV), acc.x);        \
    acc.y = fmaf((W).y, (HV), acc.y);        \
    acc.z = fmaf((W).z, (HV), acc.z);        \
    acc.w = fmaf((W).w, (HV), acc.w);

// ---------- LSTM: one block per batch element.
// 1024 threads = KG(4) k-groups x 256 hidden units. Thread (g,j) holds its
// 64-column k-slice of the packed gate weights for unit j fully in registers
// (64 x float4 = 256 VGPR). Per step: 256 reg-FMAs, LDS partial-sum reduction
// across groups, gates computed redundantly by all groups (no broadcast).
__global__ __launch_bounds__(1024, 1) void lstm_kernel(
    const float* __restrict__ xB,                    // [BATCH*SEQ] cnn features
    const float4* __restrict__ wpack,                // [257][256] (f,i,g,o)
    const float* __restrict__ bf, const float* __restrict__ bi,
    const float* __restrict__ bg, const float* __restrict__ bo,
    const float* __restrict__ w_head, const float* __restrict__ b_head,
    float* __restrict__ logits)
{
    __shared__ float4 partial[KG][HID];              // 16 KB
    __shared__ __align__(16) float hx_s[HID];        // 1 KB
    __shared__ float xlds[SEQ];                      // 4 KB
    __shared__ float red[HID];                       // 1 KB

    const int b   = blockIdx.x;
    const int tid = threadIdx.x;
    const int j   = tid & 255;
    const int g   = tid >> 8;

    // register-resident weight slice (256 VGPRs)
    float4 wreg[COLS];
    #pragma unroll
    for (int r = 0; r < COLS; ++r)
        wreg[r] = wpack[(1 + g * COLS + r) * HID + j];

    float4 bias = make_float4(0.f, 0.f, 0.f, 0.f);
    float4 w0   = make_float4(0.f, 0.f, 0.f, 0.f);
    if (g == 0) {
        bias = make_float4(bf[j], bi[j], bg[j], bo[j]);
        w0   = wpack[j];                             // k=0: input column
        hx_s[j] = 0.0f;
    }
    xlds[tid] = xB[b * SEQ + tid];                   // stage this batch's x (coalesced)
    float cx = 0.0f, hj = 0.0f;
    __syncthreads();

    const float4* __restrict__ hx4 = ((const float4*)hx_s) + g * (COLS / 4);

    for (int t = 0; t < SEQ; ++t) {
        float4 acc;
        if (g == 0) {                                // wave-uniform branch
            float xt = xlds[t];
            acc = bias;
            GATE_FMA(w0, xt);
        } else {
            acc = make_float4(0.f, 0.f, 0.f, 0.f);
        }
        #pragma unroll
        for (int r4 = 0; r4 < COLS / 4; ++r4) {      // 256 reg-FMAs
            float4 h4 = hx4[r4];
            GATE_FMA(wreg[4 * r4 + 0], h4.x);
            GATE_FMA(wreg[4 * r4 + 1], h4.y);
            GATE_FMA(wreg[4 * r4 + 2], h4.z);
            GATE_FMA(wreg[4 * r4 + 3], h4.w);
        }
        partial[g][j] = acc;
        __syncthreads();                             // partials visible

        float4 s0 = partial[0][j];
        float4 s1 = partial[1][j];
        float4 s2 = partial[2][j];
        float4 s3 = partial[3][j];
        float f  = sigmoid_fast((s0.x + s1.x) + (s2.x + s3.x));
        float i  = sigmoid_fast((s0.y + s1.y) + (s2.y + s3.y));
        float gg = tanh_fast   ((s0.z + s1.z) + (s2.z + s3.z));
        float o  = sigmoid_fast((s0.w + s1.w) + (s2.w + s3.w));
        cx = fmaf(f, cx, i * gg);
        hj = o * tanh_fast(cx);
        if (g == 0) hx_s[j] = hj;
        __syncthreads();                             // new hx visible; partial reads done
    }

    // head: logits[b] = sum_j w_head[j]*hx[j] + b_head
    if (g == 0) red[j] = w_head[j] * hj;
    __syncthreads();
    #pragma unroll
    for (int off = 128; off > 0; off >>= 1) {
        if (tid < off) red[tid] += red[tid + off];
        __syncthreads();
    }
    if (tid == 0) logits[b] = red[0] + b_head[0];
}

extern "C" void kernel_launch(void* const* d_in, const int* in_sizes, int n_in,
                              void* d_out, int out_size, void* d_ws, size_t ws_size,
                              hipStream_t stream) {
    const float* x      = (const float*)d_in[0];
    const float* w1     = (const float*)d_in[1];
    const float* b1     = (const float*)d_in[2];
    const float* w2     = (const float*)d_in[3];
    const float* b2     = (const float*)d_in[4];
    const float* w3     = (const float*)d_in[5];
    const float* b3     = (const float*)d_in[6];
    const float* w4     = (const float*)d_in[7];
    const float* b4     = (const float*)d_in[8];
    const float* w5     = (const float*)d_in[9];
    const float* b5     = (const float*)d_in[10];
    const float* w6     = (const float*)d_in[11];
    const float* b6     = (const float*)d_in[12];
    const float* w7     = (const float*)d_in[13];
    const float* b7     = (const float*)d_in[14];
    const float* w_f    = (const float*)d_in[15];
    const float* b_f    = (const float*)d_in[16];
    const float* w_i    = (const float*)d_in[17];
    const float* b_i    = (const float*)d_in[18];
    const float* w_g    = (const float*)d_in[19];
    const float* b_g    = (const float*)d_in[20];
    const float* w_o    = (const float*)d_in[21];
    const float* b_o    = (const float*)d_in[22];
    const float* w_head = (const float*)d_in[23];
    const float* b_head = (const float*)d_in[24];

    float*  out   = (float*)d_out;                   // [0..262143] cnn_features, [262144..] logits
    float4* wpack = (float4*)d_ws;                   // 1.05 MB packed gate weights

    pack_kernel<<<257, 256, 0, stream>>>(w_f, w_i, w_g, w_o, wpack);
    mlp_kernel<<<(BATCH * SEQ) / 256, 256, 0, stream>>>(
        x, w1, b1, w2, b2, w3, b3, w4, b4, w5, b5, w6, b6, w7, b7, out);
    lstm_kernel<<<BATCH, 1024, 0, stream>>>(
        out, wpack, b_f, b_i, b_g, b_o, w_head, b_head, out + BATCH * SEQ);
}